// Round 13
// baseline (50.151 us; speedup 1.0000x reference)
//
#include <hip/hip_runtime.h>

#define N_NODES 100000
#define DEG 32
#define DIM 256

typedef _Float16 f16x8 __attribute__((ext_vector_type(8)));
typedef float f32x4 __attribute__((ext_vector_type(4)));

__device__ __forceinline__ f16x8 cvt_a(float4 lo, float4 hi) {
    f16x8 af;
    af[0] = (_Float16)lo.x; af[1] = (_Float16)lo.y;
    af[2] = (_Float16)lo.z; af[3] = (_Float16)lo.w;
    af[4] = (_Float16)hi.x; af[5] = (_Float16)hi.y;
    af[6] = (_Float16)hi.z; af[7] = (_Float16)hi.w;
    return af;
}

// SINGLE-KERNEL version of the round-12 structure: the separate wprep pass
// (and its launch-dependency drain, ~4-6us of serial time per replay) is
// folded into staging. Each chunk's B fragment is gathered directly from
// raw f32 W (8 dword loads coalesced per 16-lane group, rows kbase+{0..3,
// 16..19}, col = nt*16+ll), converted and packed in-register, ds_written
// in the SAME fragment layout as before:
//   element j of lane l = W[kt*32 + 4*(l>>4) + (j&3) + 16*(j>>2)][nt*16+(l&15)]
// A uses the identical (lane,j)->k map, so any k-permutation cancels.
//
// Block = 256 threads (4 waves). Tile = 64 rows x 256 cols in EIGHT 32-col
// phases, double-buffered B (2 x 16 KB LDS), ONE barrier per phase. A held
// in f16 regs across all phases; amax/amin in regs via in-wave shuffles.
__launch_bounds__(256, 4)
__global__ void agg_kernel(const float* __restrict__ F, const float* __restrict__ Adj,
                           const float* __restrict__ W, float* __restrict__ out) {
    __shared__ _Float16 sB[2][16 * 64 * 8];   // 2 x 16384 B: chunk c=kt*2+np at ((c*64)+l)*8

    const int bx = blockIdx.x;
    const int m0 = bx * 64;
    const int t  = threadIdx.x;
    const int wv = t >> 6;
    const int l  = t & 63;
    const int lg = l >> 4;
    const int ll = l & 15;

    // ---- stage phase-0 chunks into buffer 0, gathered from raw f32 W ----
#pragma unroll
    for (int i = 0; i < 4; ++i) {
        int c = wv * 4 + i;                 // c = kt*2 + np
        int kt = c >> 1, np = c & 1;
        int col = np * 16 + ll;             // phase 0: nt = np
        int kbase = kt * 32 + 4 * lg;
        float w[8];
#pragma unroll
        for (int j = 0; j < 8; ++j)
            w[j] = W[(size_t)(kbase + (j & 3) + ((j >> 2) << 4)) * DIM + col];
        f16x8 v;
#pragma unroll
        for (int j = 0; j < 8; ++j) v[j] = (_Float16)w[j];
        *reinterpret_cast<f16x8*>(&sB[0][((size_t)c * 64 + l) * 8]) = v;
    }

    // ---- adjacency: wave reduces its OWN 16 rows (4 lanes/row, 32 B each) ----
    const int rrow = l >> 2;                // 0..15 local row within wave
    const int q    = l & 3;
    int radj = m0 + wv * 16 + rrow;
    radj = radj < N_NODES ? radj : (N_NODES - 1);
    const float4* ap = reinterpret_cast<const float4*>(Adj + (size_t)radj * DEG) + q * 2;
    float4 ad0 = ap[0], ad1 = ap[1];

    // ---- A burst: 16 dwordx4 per lane ----
    int rowA = m0 + wv * 16 + ll;
    rowA = rowA < N_NODES ? rowA : (N_NODES - 1);
    const float4* Af4 = reinterpret_cast<const float4*>(F + (size_t)rowA * DIM) + lg;
    float4 plo[8], phi[8];
#pragma unroll
    for (int kt = 0; kt < 8; ++kt) { plo[kt] = Af4[kt * 8]; phi[kt] = Af4[kt * 8 + 4]; }

    // ---- adjacency reduce in-wave (waits adj only; A still in flight) ----
    float mx = fmaxf(fmaxf(ad0.x, ad0.y), fmaxf(ad0.z, ad0.w));
    mx = fmaxf(mx, fmaxf(fmaxf(ad1.x, ad1.y), fmaxf(ad1.z, ad1.w)));
    float mn = fminf(fminf(ad0.x, ad0.y), fminf(ad0.z, ad0.w));
    mn = fminf(mn, fminf(fminf(ad1.x, ad1.y), fminf(ad1.z, ad1.w)));
    mx = fmaxf(mx, __shfl_xor(mx, 1)); mn = fminf(mn, __shfl_xor(mn, 1));
    mx = fmaxf(mx, __shfl_xor(mx, 2)); mn = fminf(mn, __shfl_xor(mn, 2));
    // epilogue row (wv*16 + 4*lg + r) was reduced by lane 16*lg+4*r
    float amaxr[4], aminr[4];
#pragma unroll
    for (int r = 0; r < 4; ++r) {
        amaxr[r] = __shfl(mx, 16 * lg + 4 * r);
        aminr[r] = __shfl(mn, 16 * lg + 4 * r);
    }

    // ---- convert A to f16 fragments ----
    f16x8 a16[8];
#pragma unroll
    for (int kt = 0; kt < 8; ++kt) a16[kt] = cvt_a(plo[kt], phi[kt]);

    __syncthreads();   // sB[0] visible

    const int rbase = wv * 16 + 4 * lg;

    for (int p = 0; p < 8; ++p) {
        // ---- issue next phase's W gathers FIRST (vmcnt; hides under compute) ----
        float w[4][8];
        if (p < 7) {
#pragma unroll
            for (int i = 0; i < 4; ++i) {
                int c = wv * 4 + i;
                int kt = c >> 1, np = c & 1;
                int col = ((p + 1) * 2 + np) * 16 + ll;
                int kbase = kt * 32 + 4 * lg;
#pragma unroll
                for (int j = 0; j < 8; ++j)
                    w[i][j] = W[(size_t)(kbase + (j & 3) + ((j >> 2) << 4)) * DIM + col];
            }
        }

        // ---- compute from sB[p&1] (lgkmcnt stream, independent of W gathers) ----
        const f16x8* Bl = reinterpret_cast<const f16x8*>(&sB[p & 1][0]) + l;
        f32x4 acc[2];
        acc[0] = (f32x4){0.f, 0.f, 0.f, 0.f};
        acc[1] = (f32x4){0.f, 0.f, 0.f, 0.f};
#pragma unroll
        for (int kt = 0; kt < 8; ++kt) {
#pragma unroll
            for (int np = 0; np < 2; ++np) {
                f16x8 b = Bl[(kt * 2 + np) * 64];
                acc[np] = __builtin_amdgcn_mfma_f32_16x16x32_f16(a16[kt], b, acc[np], 0, 0, 0);
            }
        }

        // ---- epilogue stores for phase p ----
#pragma unroll
        for (int r = 0; r < 4; ++r) {
            const int row = m0 + rbase + r;
            if (row < N_NODES) {
                float* orow = out + (size_t)row * DIM + p * 32 + ll;
#pragma unroll
                for (int np = 0; np < 2; ++np) {
                    float v = acc[np][r];
                    orow[np * 16] = fmaxf(fmaxf(amaxr[r] * v, aminr[r] * v), 0.0f);
                }
            }
        }

        // ---- cvt+pack, write into the OTHER buffer (safe pre-barrier) ----
        if (p < 7) {
#pragma unroll
            for (int i = 0; i < 4; ++i) {
                int c = wv * 4 + i;
                f16x8 v;
#pragma unroll
                for (int j = 0; j < 8; ++j) v[j] = (_Float16)w[i][j];
                *reinterpret_cast<f16x8*>(&sB[(p + 1) & 1][((size_t)c * 64 + l) * 8]) = v;
            }
            __syncthreads();   // single barrier per phase
        }
    }
}

extern "C" void kernel_launch(void* const* d_in, const int* in_sizes, int n_in,
                              void* d_out, int out_size, void* d_ws, size_t ws_size,
                              hipStream_t stream) {
    const float* F   = (const float*)d_in[0];
    const float* Adj = (const float*)d_in[1];
    const float* W   = (const float*)d_in[2];
    float* out = (float*)d_out;

    const int nblk = (N_NODES + 63) / 64;   // 1563
    hipLaunchKernelGGL(agg_kernel, dim3(nblk), dim3(256), 0, stream, F, Adj, W, out);
}